// Round 7
// baseline (232.109 us; speedup 1.0000x reference)
//
#include <hip/hip_runtime.h>

#define H 128
#define CAP 64        // fixed CSR capacity per node (Poisson(16) in-deg: P(>=64) ~ 1e-17)
#define LSTRIDE 136   // LDS row stride in bf16 elems: 272B, 16B-aligned, 2-way bank (free)
#define PSTR 132      // pool stride in floats: rl*132 -> bank offset rl*4, 2-way (free)
typedef unsigned int uint32;
typedef unsigned short ushort16;
typedef __attribute__((ext_vector_type(8))) short bf16x8;
typedef __attribute__((ext_vector_type(4))) float f32x4;

static __device__ __forceinline__ ushort16 f2bf(float f){
  uint32 u = __float_as_uint(f);
  uint32 r = (u + 0x7fff + ((u >> 16) & 1)) >> 16;   // RNE bf16 (finite values)
  return (ushort16)r;
}
static __device__ __forceinline__ float bflo(uint32 u){ return __uint_as_float(u << 16); }
static __device__ __forceinline__ float bfhi(uint32 u){ return __uint_as_float(u & 0xffff0000u); }

// y buffers are PLANE layout: 4 planes of [node][32 cols] bf16, plane stride PL=(n+1)*32.
// Each 3.2MB plane fits a per-XCD L2; k_aggcol pins planes to XCDs via blockIdx%8.

// fused setup: deg=0, gsum=0, gb[0..G]; zero sentinel rows (y0[N], ybufA/B[N] all planes);
// last 16 blocks prep W2/W3 into MFMA B-frag bf16.
__global__ __launch_bounds__(256) void k_setup(int* __restrict__ deg, float* __restrict__ gsum,
                                               const int* __restrict__ batch, int n, int G,
                                               int* __restrict__ gb, int SB,
                                               const float* __restrict__ W2, const float* __restrict__ W3,
                                               ushort16* __restrict__ wp2, ushort16* __restrict__ wp3,
                                               float4* __restrict__ y0,
                                               unsigned short* __restrict__ ybA,
                                               unsigned short* __restrict__ ybB){
  int b = blockIdx.x;
  if (b < SB){
    int i = b*256 + threadIdx.x;
    size_t PL = (size_t)(n+1)*32;
    if (i < n) deg[i] = 0;
    if (i < G*H) gsum[i] = 0.f;
    if (i < H){   // zero sentinel row N in each plane (i>>5 = plane, i&31 = col)
      size_t a = (size_t)(i>>5)*PL + (size_t)n*32 + (i&31);
      ybA[a] = 0; ybB[a] = 0;
    }
    if (i == 0) y0[n] = make_float4(0.f, 0.f, 0.f, 0.f);
    if (i <= G){
      int lo = 0, hi = n;
      while (lo < hi){ int m = (lo + hi) >> 1; if (batch[m] < i) lo = m + 1; else hi = m; }
      gb[i] = lo;
    }
  } else {
    int gid = (b - SB)*256 + threadIdx.x;   // 0..4095
    const float* W = (gid < 2048) ? W2 : W3;
    ushort16* wp   = (gid < 2048) ? wp2 : wp3;
    int tid = gid & 2047;
    int frag = tid >> 6, lane = tid & 63;
    int kt = frag >> 3, ct = frag & 7;
    int m = lane & 15, quad = lane >> 4;
    const float* wrow = &W[(kt*32 + quad*8)*H + ct*16 + m];
    ushort16 vals[8];
    #pragma unroll
    for (int j = 0; j < 8; j++) vals[j] = f2bf(wrow[j*H]);
    uint4 o;
    o.x = (uint32)vals[0] | ((uint32)vals[1] << 16);
    o.y = (uint32)vals[2] | ((uint32)vals[3] << 16);
    o.z = (uint32)vals[4] | ((uint32)vals[5] << 16);
    o.w = (uint32)vals[6] | ((uint32)vals[7] << 16);
    *(uint4*)&wp[(size_t)tid*8] = o;
  }
}

// pass 1: rank[e] = atomicAdd(deg[dst[e]]) -- coalesced rank store, one atomic chain/thread, max TLP
__global__ __launch_bounds__(256) void k_count(const int* __restrict__ dst, int E,
                                               int* __restrict__ deg, unsigned short* __restrict__ rank){
  int i = blockIdx.x*256 + threadIdx.x;
  if (i < E) rank[i] = (unsigned short)atomicAdd(&deg[dst[i]], 1);
}

// pass 2 (atomic-free): scatter csr[dst<<6 | rank] = src (fire-and-forget), plus
// extra blocks do the dinv prescale y0[i] = rsqrt(deg[i]+1) * pos[i]
__global__ __launch_bounds__(256) void k_scatter(const int* __restrict__ src, const int* __restrict__ dst,
                                                 int E, int SCB, const unsigned short* __restrict__ rank,
                                                 unsigned short* __restrict__ csr_src,
                                                 const int* __restrict__ deg, const float* __restrict__ pos,
                                                 float4* __restrict__ y0, int n){
  int b = blockIdx.x;
  if (b < SCB){
    int i = b*256 + threadIdx.x;
    if (i < E){
      int r = rank[i];
      if (r < CAP) csr_src[((size_t)dst[i] << 6) + r] = (unsigned short)src[i];
    }
  } else {
    int i = (b - SCB)*256 + threadIdx.x;
    if (i < n){
      float dv = rsqrtf((float)(deg[i] + 1));
      y0[i] = make_float4(pos[3*i]*dv, pos[3*i+1]*dv, pos[3*i+2]*dv, 0.f);
    }
  }
}

// Fused layer 1: per node, a = dinv * (y0[node] + sum_src y0[src]), then
// y1[node,c] = bf16( dinv * relu(a . W1[:,c] + b1[c]) ), stored in PLANE layout.
__global__ __launch_bounds__(256) void k_layer1(const float4* __restrict__ y0, const int* __restrict__ deg,
      const unsigned short* __restrict__ csr_src,
      const float* __restrict__ W1, const float* __restrict__ b1,
      unsigned short* __restrict__ y1, int n){
  int node = blockIdx.x*256 + threadIdx.x;
  if (node >= n) return;
  size_t PL = (size_t)(n+1)*32;
  int cnt = deg[node];
  int lo = node << 6;
  float4 own = y0[node];
  float x = own.x, y = own.y, z = own.z;
  int mm = cnt > CAP ? CAP : cnt;
  int nfull = mm >> 3, rem = mm & 7;
  #define GADD(s0,s1,s2,s3,s4,s5,s6,s7) { \
    float4 v0 = y0[s0], v1 = y0[s1], v2 = y0[s2], v3 = y0[s3]; \
    float4 v4 = y0[s4], v5 = y0[s5], v6 = y0[s6], v7 = y0[s7]; \
    x += ((v0.x+v1.x)+(v2.x+v3.x)) + ((v4.x+v5.x)+(v6.x+v7.x)); \
    y += ((v0.y+v1.y)+(v2.y+v3.y)) + ((v4.y+v5.y)+(v6.y+v7.y)); \
    z += ((v0.z+v1.z)+(v2.z+v3.z)) + ((v4.z+v5.z)+(v6.z+v7.z)); }
  if (rem){
    uint4 iv = *(const uint4*)&csr_src[lo + nfull*8];
    int s0 = (int)(iv.x & 0xffff);
    int s1 = (1 < rem)? (int)(iv.x >> 16)    : n;
    int s2 = (2 < rem)? (int)(iv.y & 0xffff) : n;
    int s3 = (3 < rem)? (int)(iv.y >> 16)    : n;
    int s4 = (4 < rem)? (int)(iv.z & 0xffff) : n;
    int s5 = (5 < rem)? (int)(iv.z >> 16)    : n;
    int s6 = (6 < rem)? (int)(iv.w & 0xffff) : n;
    int s7 = (7 < rem)? (int)(iv.w >> 16)    : n;
    GADD(s0,s1,s2,s3,s4,s5,s6,s7);
  }
  if (nfull){
    uint4 iv = *(const uint4*)&csr_src[lo];
    for (int c = 0; c < nfull; c++){
      uint4 nx = *(const uint4*)&csr_src[lo + c*8 + 8];  // prefetch (stays inside (N+1)*64 slots)
      int s0 = iv.x & 0xffff, s1 = iv.x >> 16;
      int s2 = iv.y & 0xffff, s3 = iv.y >> 16;
      int s4 = iv.z & 0xffff, s5 = iv.z >> 16;
      int s6 = iv.w & 0xffff, s7 = iv.w >> 16;
      GADD(s0,s1,s2,s3,s4,s5,s6,s7);
      iv = nx;
    }
  }
  #undef GADD
  float dn = rsqrtf((float)(cnt + 1));
  x *= dn; y *= dn; z *= dn;
  for (int c8 = 0; c8 < 16; c8++){
    float4 wa0 = *(const float4*)&W1[c8*8];
    float4 wa1 = *(const float4*)&W1[c8*8+4];
    float4 wb0 = *(const float4*)&W1[H + c8*8];
    float4 wb1 = *(const float4*)&W1[H + c8*8+4];
    float4 wc0 = *(const float4*)&W1[2*H + c8*8];
    float4 wc1 = *(const float4*)&W1[2*H + c8*8+4];
    float4 bb0 = *(const float4*)&b1[c8*8];
    float4 bb1 = *(const float4*)&b1[c8*8+4];
    float o0 = fmaxf(x*wa0.x + y*wb0.x + z*wc0.x + bb0.x, 0.f) * dn;
    float o1 = fmaxf(x*wa0.y + y*wb0.y + z*wc0.y + bb0.y, 0.f) * dn;
    float o2 = fmaxf(x*wa0.z + y*wb0.z + z*wc0.z + bb0.z, 0.f) * dn;
    float o3 = fmaxf(x*wa0.w + y*wb0.w + z*wc0.w + bb0.w, 0.f) * dn;
    float o4 = fmaxf(x*wa1.x + y*wb1.x + z*wc1.x + bb1.x, 0.f) * dn;
    float o5 = fmaxf(x*wa1.y + y*wb1.y + z*wc1.y + bb1.y, 0.f) * dn;
    float o6 = fmaxf(x*wa1.z + y*wb1.z + z*wc1.z + bb1.z, 0.f) * dn;
    float o7 = fmaxf(x*wa1.w + y*wb1.w + z*wc1.w + bb1.w, 0.f) * dn;
    uint4 o;
    o.x = (uint32)f2bf(o0) | ((uint32)f2bf(o1) << 16);
    o.y = (uint32)f2bf(o2) | ((uint32)f2bf(o3) << 16);
    o.z = (uint32)f2bf(o4) | ((uint32)f2bf(o5) << 16);
    o.w = (uint32)f2bf(o6) | ((uint32)f2bf(o7) << 16);
    // plane layout store: plane = c8>>2, in-plane col = (c8&3)*8
    *(uint4*)&y1[(size_t)(c8>>2)*PL + (size_t)node*32 + (c8&3)*8] = o;
  }
}

// Plane-partitioned aggregation: block handles 16 nodes x ONE 32-col plane.
// blockIdx%8 -> (plane = c>>1, half = c&1): round-robin XCD dispatch pins each
// 3.2MB plane to ~2 XCDs' L2 (perf heuristic only; correctness placement-free).
// out: agg[plane][node][32] = bf16( dn * (self + sum_neighbors) )
__global__ __launch_bounds__(128) void k_aggcol(const unsigned short* __restrict__ y,
      const int* __restrict__ deg, const unsigned short* __restrict__ csr_src,
      unsigned short* __restrict__ agg, int n){
  int b = blockIdx.x;
  int c = b & 7;
  int plane = c >> 1;
  int node16 = ((b >> 3)*2 + (c & 1)) * 16;
  int tid = threadIdx.x;           // 0..127
  int nl = tid >> 3;               // local node 0..15
  int node = node16 + nl;
  if (node >= n) return;
  int l4 = (tid & 7) * 4;          // col offset in plane: 0..28
  size_t PL = (size_t)(n+1)*32;
  const unsigned short* yp = y + (size_t)plane*PL + l4;

  float a0=0,a1=0,a2=0,a3=0;
  #define ADDU2(u) { a0+=bflo(u.x); a1+=bfhi(u.x); a2+=bflo(u.y); a3+=bfhi(u.y); }
  #define GATH8(s0,s1,s2,s3,s4,s5,s6,s7) { \
    uint2 u0 = *(const uint2*)&yp[(size_t)(s0)*32]; \
    uint2 u1 = *(const uint2*)&yp[(size_t)(s1)*32]; \
    uint2 u2 = *(const uint2*)&yp[(size_t)(s2)*32]; \
    uint2 u3 = *(const uint2*)&yp[(size_t)(s3)*32]; \
    uint2 u4 = *(const uint2*)&yp[(size_t)(s4)*32]; \
    uint2 u5 = *(const uint2*)&yp[(size_t)(s5)*32]; \
    uint2 u6 = *(const uint2*)&yp[(size_t)(s6)*32]; \
    uint2 u7 = *(const uint2*)&yp[(size_t)(s7)*32]; \
    ADDU2(u0); ADDU2(u1); ADDU2(u2); ADDU2(u3); \
    ADDU2(u4); ADDU2(u5); ADDU2(u6); ADDU2(u7); }
  int cnt = deg[node];
  int lo = node << 6;
  uint2 uo = *(const uint2*)&yp[(size_t)node*32];   // self row
  ADDU2(uo);
  int mm = cnt > CAP ? CAP : cnt;
  int nfull = mm >> 3, rem = mm & 7;
  if (rem){
    uint4 iv = *(const uint4*)&csr_src[lo + nfull*8];
    int s0 = (int)(iv.x & 0xffff);
    int s1 = (1 < rem)? (int)(iv.x >> 16)    : n;
    int s2 = (2 < rem)? (int)(iv.y & 0xffff) : n;
    int s3 = (3 < rem)? (int)(iv.y >> 16)    : n;
    int s4 = (4 < rem)? (int)(iv.z & 0xffff) : n;
    int s5 = (5 < rem)? (int)(iv.z >> 16)    : n;
    int s6 = (6 < rem)? (int)(iv.w & 0xffff) : n;
    int s7 = (7 < rem)? (int)(iv.w >> 16)    : n;
    GATH8(s0,s1,s2,s3,s4,s5,s6,s7);
  }
  if (nfull){
    uint4 iv = *(const uint4*)&csr_src[lo];
    for (int cc = 0; cc < nfull; cc++){
      uint4 nx = *(const uint4*)&csr_src[lo + cc*8 + 8];  // prefetch next chunk's indices
      int s0 = iv.x & 0xffff, s1 = iv.x >> 16;
      int s2 = iv.y & 0xffff, s3 = iv.y >> 16;
      int s4 = iv.z & 0xffff, s5 = iv.z >> 16;
      int s6 = iv.w & 0xffff, s7 = iv.w >> 16;
      GATH8(s0,s1,s2,s3,s4,s5,s6,s7);
      iv = nx;
    }
  }
  #undef GATH8
  #undef ADDU2
  float dn = rsqrtf((float)(cnt + 1));
  uint2 o;
  o.x = (uint32)f2bf(a0*dn) | ((uint32)f2bf(a1*dn) << 16);
  o.y = (uint32)f2bf(a2*dn) | ((uint32)f2bf(a3*dn) << 16);
  *(uint2*)&agg[(size_t)plane*PL + (size_t)node*32 + l4] = o;
}

// Dense MFMA over aggregated rows (coalesced read of agg planes -> LDS -> MFMA).
// POOL=0: out tile -> plane-layout bf16 stores (next layer's gather input)
// POOL=1: relu(aW+b) -> LDS tile -> parallel segmented atomicAdd into gsum
template<int POOL>
__global__ __launch_bounds__(256) void k_dense(const unsigned short* __restrict__ agg,
      const int* __restrict__ deg, const ushort16* __restrict__ wp, const float* __restrict__ bias,
      unsigned short* __restrict__ yout, const int* __restrict__ batch, float* __restrict__ gsum, int n){
  __shared__ unsigned short As[16*LSTRIDE];
  __shared__ float pool[POOL ? 16*PSTR : 1];
  __shared__ unsigned short outs[POOL ? 1 : 16*PSTR];
  __shared__ int sbatch[POOL ? 16 : 1];
  __shared__ float sdinv[POOL ? 1 : 16];
  int tid = threadIdx.x;
  int node16 = blockIdx.x*16;
  int nl = tid >> 4;
  int node = node16 + nl;
  int f8 = (tid & 15) * 8;
  size_t PL = (size_t)(n+1)*32;

  if (tid < 16){
    int nn = node16 + tid;
    if (POOL) sbatch[tid] = (nn < n) ? batch[nn] : -1;
    else      sdinv[tid]  = (nn < n) ? rsqrtf((float)(deg[nn] + 1)) : 0.f;
  }
  // phase A': coalesced read of the 4 plane slices for this node row
  uint4 v = make_uint4(0,0,0,0);
  if (node < n) v = *(const uint4*)&agg[(size_t)(f8>>5)*PL + (size_t)node*32 + (f8&31)];
  *(uint4*)&As[nl*LSTRIDE + f8] = v;
  __syncthreads();

  // phase B: MFMA — wave w handles col-tiles {2w, 2w+1} over the 16 staged rows
  int wave = tid >> 6;
  int lane = tid & 63;
  int m = lane & 15, quad = lane >> 4;
  f32x4 acc0 = {0.f,0.f,0.f,0.f}, acc1 = {0.f,0.f,0.f,0.f};
  int ct0 = wave*2, ct1 = wave*2 + 1;
  #pragma unroll
  for (int kt = 0; kt < 4; kt++){
    bf16x8 af = *(const bf16x8*)&As[m*LSTRIDE + kt*32 + quad*8];
    bf16x8 b0 = *(const bf16x8*)&wp[(size_t)((kt*8+ct0)*64 + lane)*8];
    bf16x8 b1 = *(const bf16x8*)&wp[(size_t)((kt*8+ct1)*64 + lane)*8];
    acc0 = __builtin_amdgcn_mfma_f32_16x16x32_bf16(af, b0, acc0, 0, 0, 0);
    acc1 = __builtin_amdgcn_mfma_f32_16x16x32_bf16(af, b1, acc1, 0, 0, 0);
  }
  // C/D layout: col = ct*16 + m, row (in tile) = quad*4 + r
  #pragma unroll
  for (int j = 0; j < 2; j++){
    int ct = wave*2 + j;
    int col = ct*16 + m;
    float bv = bias[col];
    f32x4 ac = j ? acc1 : acc0;
    #pragma unroll
    for (int r = 0; r < 4; r++){
      int rl = quad*4 + r;
      int orow = node16 + rl;
      if (orow < n){
        float vv = fmaxf(ac[r] + bv, 0.f);
        if (POOL) pool[rl*PSTR + col] = vv;
        else      outs[rl*PSTR + col] = f2bf(vv * sdinv[rl]);
      }
    }
  }
  __syncthreads();
  if (POOL){
    int col = tid & 127;
    int half = tid >> 7;
    float run = 0.f; int gprev = -1;
    for (int r = half*8; r < half*8 + 8; r++){
      int g = sbatch[r];
      if (g < 0) break;
      if (g != gprev){
        if (gprev >= 0) atomicAdd(&gsum[gprev*H + col], run);
        run = 0.f; gprev = g;
      }
      run += pool[r*PSTR + col];
    }
    if (gprev >= 0) atomicAdd(&gsum[gprev*H + col], run);
  } else {
    // plane-layout coalesced store: thread t writes row t>>4, 8 bf16 into plane f8>>5
    int row = tid >> 4;
    int orow = node16 + row;
    if (orow < n){
      const unsigned short* sp = &outs[row*PSTR + f8];
      uint4 o;
      o.x = (uint32)sp[0] | ((uint32)sp[1] << 16);
      o.y = (uint32)sp[2] | ((uint32)sp[3] << 16);
      o.z = (uint32)sp[4] | ((uint32)sp[5] << 16);
      o.w = (uint32)sp[6] | ((uint32)sp[7] << 16);
      *(uint4*)&yout[(size_t)(f8>>5)*PL + (size_t)orow*32 + (f8&31)] = o;
    }
  }
}

// MLP head: relu((gsum/cnt) @ Wl1 + bl1) @ Wl2 + bl2
__global__ __launch_bounds__(64) void k_head(const float* __restrict__ gsum, const int* __restrict__ gb,
            const float* __restrict__ Wl1, const float* __restrict__ bl1,
            const float* __restrict__ Wl2, const float* __restrict__ bl2,
            float* __restrict__ out){
  int g = blockIdx.x;
  int t = threadIdx.x;
  __shared__ float gs[H];
  __shared__ float h1[64];
  float inv = 1.f / fmaxf((float)(gb[g+1] - gb[g]), 1.f);
  gs[t]      = gsum[g*H + t]      * inv;
  gs[64 + t] = gsum[g*H + 64 + t] * inv;
  __syncthreads();
  float acc = bl1[t];
  for (int k = 0; k < H; k++) acc += gs[k] * Wl1[k*64 + t];
  h1[t] = fmaxf(acc, 0.f);
  __syncthreads();
  if (t < 10){
    float o = bl2[t];
    for (int j = 0; j < 64; j++) o += h1[j] * Wl2[j*10 + t];
    out[g*10 + t] = o;
  }
}

extern "C" void kernel_launch(void* const* d_in, const int* in_sizes, int n_in,
                              void* d_out, int out_size, void* d_ws, size_t ws_size,
                              hipStream_t stream){
  const float* pos = (const float*)d_in[0];
  const int*  ei   = (const int*)d_in[1];
  const int*  batch= (const int*)d_in[2];
  const float* W1 = (const float*)d_in[3];
  const float* b1 = (const float*)d_in[4];
  const float* W2 = (const float*)d_in[5];
  const float* b2 = (const float*)d_in[6];
  const float* W3 = (const float*)d_in[7];
  const float* b3 = (const float*)d_in[8];
  const float* Wl1 = (const float*)d_in[9];
  const float* bl1 = (const float*)d_in[10];
  const float* Wl2 = (const float*)d_in[11];
  const float* bl2 = (const float*)d_in[12];
  float* out = (float*)d_out;

  int N = in_sizes[0] / 3;     // 50000 (< 65535 required for ushort CSR + sentinel)
  int E = in_sizes[1] / 2;     // 800000
  int G = out_size / 10;       // 64
  int SB = (N + 255) / 256;    // setup blocks
  int SCB = (E + 255) / 256;   // scatter blocks
  int PB = (N + 255) / 256;    // prescale blocks
  int NG2 = (N + 31) / 32;     // node-pair groups for k_aggcol

  // workspace carve (~49 MB)
  char* p = (char*)d_ws;
  auto carve = [&](size_t bytes)->char* { char* q = p; p += (bytes + 255) & ~(size_t)255; return q; };
  int*            deg     = (int*)     carve(sizeof(int)    * (size_t)N);
  int*            gb      = (int*)     carve(sizeof(int)    * (size_t)(G+1));
  float*          gsum    = (float*)   carve(sizeof(float)  * (size_t)G * H);
  unsigned short* csr_src = (unsigned short*)carve(sizeof(unsigned short) * (size_t)(N+1) * CAP);
  unsigned short* rank    = (unsigned short*)carve(sizeof(unsigned short) * (size_t)E);
  float4*         y0      = (float4*)  carve(sizeof(float4) * (size_t)(N+1));                    // +1 sentinel
  unsigned short* ybufA   = (unsigned short*)carve(sizeof(unsigned short) * (size_t)(N+1) * H);  // plane layout
  unsigned short* ybufB   = (unsigned short*)carve(sizeof(unsigned short) * (size_t)(N+1) * H);  // plane layout
  unsigned short* aggbuf  = (unsigned short*)carve(sizeof(unsigned short) * (size_t)(N+1) * H);  // plane layout
  ushort16*       wp2     = (ushort16*)carve(sizeof(ushort16) * 16384);
  ushort16*       wp3     = (ushort16*)carve(sizeof(ushort16) * 16384);

  const int* src = ei;
  const int* dst = ei + E;

  hipLaunchKernelGGL(k_setup, dim3(SB + 16), dim3(256), 0, stream,
                     deg, gsum, batch, N, G, gb, SB, W2, W3, wp2, wp3,
                     y0, ybufA, ybufB);

  // pass 1: per-edge rank via atomic (coalesced rank store)
  hipLaunchKernelGGL(k_count, dim3((E+255)/256), dim3(256), 0, stream, dst, E, deg, rank);

  // pass 2: atomic-free scatter into fixed-capacity CSR + fused dinv prescale
  hipLaunchKernelGGL(k_scatter, dim3(SCB + PB), dim3(256), 0, stream,
                     src, dst, E, SCB, rank, csr_src, deg, pos, y0, N);

  // layer 1 (aggregate-first 3-wide gather + fused 3->128 dense, plane-layout out)
  hipLaunchKernelGGL(k_layer1, dim3((N+255)/256), dim3(256), 0, stream, y0, deg, csr_src, W1, b1, ybufA, N);

  // layer 2: plane-partitioned aggregation, then dense MFMA
  hipLaunchKernelGGL(k_aggcol, dim3(NG2*8), dim3(128), 0, stream, ybufA, deg, csr_src, aggbuf, N);
  hipLaunchKernelGGL(k_dense<0>, dim3((N+15)/16), dim3(256), 0, stream,
                     aggbuf, deg, wp2, b2, ybufB, (const int*)nullptr, (float*)nullptr, N);

  // layer 3: same, pooled into gsum
  hipLaunchKernelGGL(k_aggcol, dim3(NG2*8), dim3(128), 0, stream, ybufB, deg, csr_src, aggbuf, N);
  hipLaunchKernelGGL(k_dense<1>, dim3((N+15)/16), dim3(256), 0, stream,
                     aggbuf, deg, wp3, b3, (unsigned short*)nullptr, batch, gsum, N);

  hipLaunchKernelGGL(k_head, dim3(G), dim3(64), 0, stream, gsum, gb, Wl1, bl1, Wl2, bl2, out);
}

// Round 8
// 229.099 us; speedup vs baseline: 1.0131x; 1.0131x over previous
//
#include <hip/hip_runtime.h>

#define H 128
#define CAP 64        // fixed CSR capacity per node (Poisson(16) in-deg: P(>=64) ~ 1e-17)
#define LSTRIDE 136   // LDS row stride in bf16 elems: 272B, 16B-aligned, 2-way bank (free)
#define PSTR 132      // pool stride in floats: rl*132 -> bank offset rl*4, 2-way (free)
typedef unsigned int uint32;
typedef unsigned short ushort16;
typedef __attribute__((ext_vector_type(8))) short bf16x8;
typedef __attribute__((ext_vector_type(4))) float f32x4;

static __device__ __forceinline__ ushort16 f2bf(float f){
  uint32 u = __float_as_uint(f);
  uint32 r = (u + 0x7fff + ((u >> 16) & 1)) >> 16;   // RNE bf16 (finite values)
  return (ushort16)r;
}
static __device__ __forceinline__ float bflo(uint32 u){ return __uint_as_float(u << 16); }
static __device__ __forceinline__ float bfhi(uint32 u){ return __uint_as_float(u & 0xffff0000u); }

// fused setup: deg=0, gsum=0, gb[0..G]; zero sentinel rows (y0[N], ybufA[N], ybufB[N]);
// last 16 blocks prep W2/W3 into MFMA B-frag bf16.
__global__ __launch_bounds__(256) void k_setup(int* __restrict__ deg, float* __restrict__ gsum,
                                               const int* __restrict__ batch, int n, int G,
                                               int* __restrict__ gb, int SB,
                                               const float* __restrict__ W2, const float* __restrict__ W3,
                                               ushort16* __restrict__ wp2, ushort16* __restrict__ wp3,
                                               float4* __restrict__ y0,
                                               unsigned short* __restrict__ ybA,
                                               unsigned short* __restrict__ ybB){
  int b = blockIdx.x;
  if (b < SB){
    int i = b*256 + threadIdx.x;
    if (i < n) deg[i] = 0;
    if (i < G*H) gsum[i] = 0.f;
    if (i < H){ ybA[(size_t)n*H + i] = 0; ybB[(size_t)n*H + i] = 0; }
    if (i == 0) y0[n] = make_float4(0.f, 0.f, 0.f, 0.f);
    if (i <= G){
      int lo = 0, hi = n;
      while (lo < hi){ int m = (lo + hi) >> 1; if (batch[m] < i) lo = m + 1; else hi = m; }
      gb[i] = lo;
    }
  } else {
    int gid = (b - SB)*256 + threadIdx.x;   // 0..4095
    const float* W = (gid < 2048) ? W2 : W3;
    ushort16* wp   = (gid < 2048) ? wp2 : wp3;
    int tid = gid & 2047;
    int frag = tid >> 6, lane = tid & 63;
    int kt = frag >> 3, ct = frag & 7;
    int m = lane & 15, quad = lane >> 4;
    const float* wrow = &W[(kt*32 + quad*8)*H + ct*16 + m];
    ushort16 vals[8];
    #pragma unroll
    for (int j = 0; j < 8; j++) vals[j] = f2bf(wrow[j*H]);
    uint4 o;
    o.x = (uint32)vals[0] | ((uint32)vals[1] << 16);
    o.y = (uint32)vals[2] | ((uint32)vals[3] << 16);
    o.z = (uint32)vals[4] | ((uint32)vals[5] << 16);
    o.w = (uint32)vals[6] | ((uint32)vals[7] << 16);
    *(uint4*)&wp[(size_t)tid*8] = o;
  }
}

// one-pass CSR fill, 1 edge/thread: full grid (12500 waves) hides the atomic+store chain
__global__ __launch_bounds__(256) void k_fill(const int* __restrict__ src, const int* __restrict__ dst,
                                              int E, int* __restrict__ deg,
                                              unsigned short* __restrict__ csr_src){
  int i = blockIdx.x*256 + threadIdx.x;
  if (i < E){
    int d = dst[i];
    int slot = atomicAdd(&deg[d], 1);
    if (slot < CAP) csr_src[((size_t)d << 6) + slot] = (unsigned short)src[i];
  }
}

// dinv prescale: y0[i] = rsqrt(deg[i]+1) * pos[i]
__global__ __launch_bounds__(256) void k_pre(const int* __restrict__ deg, const float* __restrict__ pos,
                                             float4* __restrict__ y0, int n){
  int i = blockIdx.x*256 + threadIdx.x;
  if (i < n){
    float dv = rsqrtf((float)(deg[i] + 1));
    y0[i] = make_float4(pos[3*i]*dv, pos[3*i+1]*dv, pos[3*i+2]*dv, 0.f);
  }
}

// Fused layer 1: per node, a = dinv * (y0[node] + sum_src y0[src]), then
// y1[node,c] = bf16( dinv * relu(a . W1[:,c] + b1[c]) ) for all 128 cols (W1/b1 wave-uniform).
// Self-contribution added directly; tail chunk index-clamped to sentinel n (zero row).
__global__ __launch_bounds__(256) void k_layer1(const float4* __restrict__ y0, const int* __restrict__ deg,
      const unsigned short* __restrict__ csr_src,
      const float* __restrict__ W1, const float* __restrict__ b1,
      ushort16* __restrict__ y1, int n){
  int node = blockIdx.x*256 + threadIdx.x;
  if (node >= n) return;
  int cnt = deg[node];
  int lo = node << 6;
  float4 own = y0[node];
  float x = own.x, y = own.y, z = own.z;
  int mm = cnt > CAP ? CAP : cnt;
  int nfull = mm >> 3, rem = mm & 7;
  #define GADD(s0,s1,s2,s3,s4,s5,s6,s7) { \
    float4 v0 = y0[s0], v1 = y0[s1], v2 = y0[s2], v3 = y0[s3]; \
    float4 v4 = y0[s4], v5 = y0[s5], v6 = y0[s6], v7 = y0[s7]; \
    x += ((v0.x+v1.x)+(v2.x+v3.x)) + ((v4.x+v5.x)+(v6.x+v7.x)); \
    y += ((v0.y+v1.y)+(v2.y+v3.y)) + ((v4.y+v5.y)+(v6.y+v7.y)); \
    z += ((v0.z+v1.z)+(v2.z+v3.z)) + ((v4.z+v5.z)+(v6.z+v7.z)); }
  if (rem){
    uint4 iv = *(const uint4*)&csr_src[lo + nfull*8];
    int s0 = (int)(iv.x & 0xffff);
    int s1 = (1 < rem)? (int)(iv.x >> 16)    : n;
    int s2 = (2 < rem)? (int)(iv.y & 0xffff) : n;
    int s3 = (3 < rem)? (int)(iv.y >> 16)    : n;
    int s4 = (4 < rem)? (int)(iv.z & 0xffff) : n;
    int s5 = (5 < rem)? (int)(iv.z >> 16)    : n;
    int s6 = (6 < rem)? (int)(iv.w & 0xffff) : n;
    int s7 = (7 < rem)? (int)(iv.w >> 16)    : n;
    GADD(s0,s1,s2,s3,s4,s5,s6,s7);
  }
  if (nfull){
    uint4 iv = *(const uint4*)&csr_src[lo];
    for (int c = 0; c < nfull; c++){
      uint4 nx = *(const uint4*)&csr_src[lo + c*8 + 8];  // prefetch (stays inside (N+1)*64 slots)
      int s0 = iv.x & 0xffff, s1 = iv.x >> 16;
      int s2 = iv.y & 0xffff, s3 = iv.y >> 16;
      int s4 = iv.z & 0xffff, s5 = iv.z >> 16;
      int s6 = iv.w & 0xffff, s7 = iv.w >> 16;
      GADD(s0,s1,s2,s3,s4,s5,s6,s7);
      iv = nx;
    }
  }
  #undef GADD
  float dn = rsqrtf((float)(cnt + 1));
  x *= dn; y *= dn; z *= dn;
  ushort16* rowp = &y1[(size_t)node*H];
  for (int c8 = 0; c8 < 16; c8++){
    float4 wa0 = *(const float4*)&W1[c8*8];
    float4 wa1 = *(const float4*)&W1[c8*8+4];
    float4 wb0 = *(const float4*)&W1[H + c8*8];
    float4 wb1 = *(const float4*)&W1[H + c8*8+4];
    float4 wc0 = *(const float4*)&W1[2*H + c8*8];
    float4 wc1 = *(const float4*)&W1[2*H + c8*8+4];
    float4 bb0 = *(const float4*)&b1[c8*8];
    float4 bb1 = *(const float4*)&b1[c8*8+4];
    float o0 = fmaxf(x*wa0.x + y*wb0.x + z*wc0.x + bb0.x, 0.f) * dn;
    float o1 = fmaxf(x*wa0.y + y*wb0.y + z*wc0.y + bb0.y, 0.f) * dn;
    float o2 = fmaxf(x*wa0.z + y*wb0.z + z*wc0.z + bb0.z, 0.f) * dn;
    float o3 = fmaxf(x*wa0.w + y*wb0.w + z*wc0.w + bb0.w, 0.f) * dn;
    float o4 = fmaxf(x*wa1.x + y*wb1.x + z*wc1.x + bb1.x, 0.f) * dn;
    float o5 = fmaxf(x*wa1.y + y*wb1.y + z*wc1.y + bb1.y, 0.f) * dn;
    float o6 = fmaxf(x*wa1.z + y*wb1.z + z*wc1.z + bb1.z, 0.f) * dn;
    float o7 = fmaxf(x*wa1.w + y*wb1.w + z*wc1.w + bb1.w, 0.f) * dn;
    uint4 o;
    o.x = (uint32)f2bf(o0) | ((uint32)f2bf(o1) << 16);
    o.y = (uint32)f2bf(o2) | ((uint32)f2bf(o3) << 16);
    o.z = (uint32)f2bf(o4) | ((uint32)f2bf(o5) << 16);
    o.w = (uint32)f2bf(o6) | ((uint32)f2bf(o7) << 16);
    *(uint4*)&rowp[c8*8] = o;
  }
}

// Fused aggregate + MFMA dense (full gather parallelism: 16 nodes/block, 16 lanes/node, one pass).
// Self row added directly (coalesced); tail chunk clamped to sentinel n (zero row).
// POOL=0: yout tile staged in LDS then coalesced 16B/lane bf16 stores (layer 2)
// POOL=1: relu(aW+b) -> LDS tile -> parallel segmented atomicAdd into gsum (layer 3 + pool numerator)
template<int POOL>
__global__ __launch_bounds__(256) void k_aggdense(const ushort16* __restrict__ y, const int* __restrict__ deg,
      const unsigned short* __restrict__ csr_src, const ushort16* __restrict__ wp,
      const float* __restrict__ bias,
      ushort16* __restrict__ yout, const int* __restrict__ batch, float* __restrict__ gsum, int n){
  __shared__ unsigned short As[16*LSTRIDE];          // 4352 B
  __shared__ float pool[POOL ? 16*PSTR : 1];         // 8448 B (POOL only)
  __shared__ unsigned short outs[POOL ? 1 : 16*PSTR];// 4224 B (non-POOL: staged bf16 out tile)
  __shared__ int sbatch[POOL ? 16 : 1];
  __shared__ float sdinv[POOL ? 1 : 16];
  int tid = threadIdx.x;
  int node16 = blockIdx.x*16;
  int nl = tid >> 4;                 // local node 0..15
  int node = node16 + nl;
  int f8 = (tid & 15) * 8;

  if (tid < 16){
    int nn = node16 + tid;
    if (POOL) sbatch[tid] = (nn < n) ? batch[nn] : -1;
    else      sdinv[tid]  = (nn < n) ? rsqrtf((float)(deg[nn] + 1)) : 0.f;
  }

  // ---- phase A: aggregate (self row + branchless 8-wide chunks, clamped tail first) ----
  float a0=0,a1=0,a2=0,a3=0,a4=0,a5=0,a6=0,a7=0;
  float dn = 0.f;
  #define ADDU(u) { a0+=bflo(u.x); a1+=bfhi(u.x); a2+=bflo(u.y); a3+=bfhi(u.y); \
                    a4+=bflo(u.z); a5+=bfhi(u.z); a6+=bflo(u.w); a7+=bfhi(u.w); }
  #define GATHER8(s0,s1,s2,s3,s4,s5,s6,s7) { \
    uint4 u0 = *(const uint4*)&y[(size_t)(s0)*H + f8]; \
    uint4 u1 = *(const uint4*)&y[(size_t)(s1)*H + f8]; \
    uint4 u2 = *(const uint4*)&y[(size_t)(s2)*H + f8]; \
    uint4 u3 = *(const uint4*)&y[(size_t)(s3)*H + f8]; \
    uint4 u4 = *(const uint4*)&y[(size_t)(s4)*H + f8]; \
    uint4 u5 = *(const uint4*)&y[(size_t)(s5)*H + f8]; \
    uint4 u6 = *(const uint4*)&y[(size_t)(s6)*H + f8]; \
    uint4 u7 = *(const uint4*)&y[(size_t)(s7)*H + f8]; \
    ADDU(u0); ADDU(u1); ADDU(u2); ADDU(u3); \
    ADDU(u4); ADDU(u5); ADDU(u6); ADDU(u7); }
  if (node < n){
    int cnt = deg[node];
    int lo = node << 6;
    dn = rsqrtf((float)(cnt + 1));
    uint4 uo = *(const uint4*)&y[(size_t)node*H + f8];   // self row (coalesced)
    ADDU(uo);
    int mm = cnt > CAP ? CAP : cnt;
    int nfull = mm >> 3, rem = mm & 7;
    if (rem){
      uint4 iv = *(const uint4*)&csr_src[lo + nfull*8];
      int s0 = (int)(iv.x & 0xffff);
      int s1 = (1 < rem)? (int)(iv.x >> 16)    : n;
      int s2 = (2 < rem)? (int)(iv.y & 0xffff) : n;
      int s3 = (3 < rem)? (int)(iv.y >> 16)    : n;
      int s4 = (4 < rem)? (int)(iv.z & 0xffff) : n;
      int s5 = (5 < rem)? (int)(iv.z >> 16)    : n;
      int s6 = (6 < rem)? (int)(iv.w & 0xffff) : n;
      int s7 = (7 < rem)? (int)(iv.w >> 16)    : n;
      GATHER8(s0,s1,s2,s3,s4,s5,s6,s7);
    }
    if (nfull){
      uint4 iv = *(const uint4*)&csr_src[lo];
      for (int c = 0; c < nfull; c++){
        uint4 nx = *(const uint4*)&csr_src[lo + c*8 + 8];  // prefetch next chunk's indices
        int s0 = iv.x & 0xffff, s1 = iv.x >> 16;
        int s2 = iv.y & 0xffff, s3 = iv.y >> 16;
        int s4 = iv.z & 0xffff, s5 = iv.z >> 16;
        int s6 = iv.w & 0xffff, s7 = iv.w >> 16;
        GATHER8(s0,s1,s2,s3,s4,s5,s6,s7);
        iv = nx;
      }
    }
  }
  #undef GATHER8
  #undef ADDU
  uint4 o;
  o.x = (uint32)f2bf(a0*dn) | ((uint32)f2bf(a1*dn) << 16);
  o.y = (uint32)f2bf(a2*dn) | ((uint32)f2bf(a3*dn) << 16);
  o.z = (uint32)f2bf(a4*dn) | ((uint32)f2bf(a5*dn) << 16);
  o.w = (uint32)f2bf(a6*dn) | ((uint32)f2bf(a7*dn) << 16);
  *(uint4*)&As[nl*LSTRIDE + f8] = o;
  __syncthreads();

  // ---- phase B: MFMA — wave w handles col-tiles {2w, 2w+1} over the 16 staged rows ----
  int wave = tid >> 6;
  int lane = tid & 63;
  int m = lane & 15, quad = lane >> 4;
  f32x4 acc0 = {0.f,0.f,0.f,0.f}, acc1 = {0.f,0.f,0.f,0.f};
  int ct0 = wave*2, ct1 = wave*2 + 1;
  #pragma unroll
  for (int kt = 0; kt < 4; kt++){
    bf16x8 af = *(const bf16x8*)&As[m*LSTRIDE + kt*32 + quad*8];
    bf16x8 b0 = *(const bf16x8*)&wp[(size_t)((kt*8+ct0)*64 + lane)*8];
    bf16x8 b1 = *(const bf16x8*)&wp[(size_t)((kt*8+ct1)*64 + lane)*8];
    acc0 = __builtin_amdgcn_mfma_f32_16x16x32_bf16(af, b0, acc0, 0, 0, 0);
    acc1 = __builtin_amdgcn_mfma_f32_16x16x32_bf16(af, b1, acc1, 0, 0, 0);
  }
  // C/D layout: col = ct*16 + m, row (in tile) = quad*4 + r
  #pragma unroll
  for (int j = 0; j < 2; j++){
    int ct = wave*2 + j;
    int col = ct*16 + m;
    float bv = bias[col];
    f32x4 ac = j ? acc1 : acc0;
    #pragma unroll
    for (int r = 0; r < 4; r++){
      int rl = quad*4 + r;
      int orow = node16 + rl;
      if (orow < n){
        float v = fmaxf(ac[r] + bv, 0.f);
        if (POOL) pool[rl*PSTR + col] = v;                            // one lane per (row,col)
        else      outs[rl*PSTR + col] = f2bf(v * sdinv[rl]);
      }
    }
  }
  __syncthreads();
  if (POOL){
    // parallel segmented tail: 256 threads = 128 cols x 2 row-halves
    int col = tid & 127;
    int half = tid >> 7;
    float run = 0.f; int gprev = -1;
    for (int r = half*8; r < half*8 + 8; r++){
      int g = sbatch[r];
      if (g < 0) break;            // tail rows only
      if (g != gprev){
        if (gprev >= 0) atomicAdd(&gsum[gprev*H + col], run);
        run = 0.f; gprev = g;
      }
      run += pool[r*PSTR + col];
    }
    if (gprev >= 0) atomicAdd(&gsum[gprev*H + col], run);
  } else {
    // coalesced store: thread t writes row t>>4, 8 bf16 at (t&15)*8
    int row = tid >> 4;
    int orow = node16 + row;
    if (orow < n){
      const unsigned short* sp = &outs[row*PSTR + f8];
      uint4 v;
      v.x = (uint32)sp[0] | ((uint32)sp[1] << 16);
      v.y = (uint32)sp[2] | ((uint32)sp[3] << 16);
      v.z = (uint32)sp[4] | ((uint32)sp[5] << 16);
      v.w = (uint32)sp[6] | ((uint32)sp[7] << 16);
      *(uint4*)&yout[(size_t)orow*H + f8] = v;
    }
  }
}

// MLP head: relu((gsum/cnt) @ Wl1 + bl1) @ Wl2 + bl2
__global__ __launch_bounds__(64) void k_head(const float* __restrict__ gsum, const int* __restrict__ gb,
            const float* __restrict__ Wl1, const float* __restrict__ bl1,
            const float* __restrict__ Wl2, const float* __restrict__ bl2,
            float* __restrict__ out){
  int g = blockIdx.x;
  int t = threadIdx.x;
  __shared__ float gs[H];
  __shared__ float h1[64];
  float inv = 1.f / fmaxf((float)(gb[g+1] - gb[g]), 1.f);
  gs[t]      = gsum[g*H + t]      * inv;
  gs[64 + t] = gsum[g*H + 64 + t] * inv;
  __syncthreads();
  float acc = bl1[t];
  for (int k = 0; k < H; k++) acc += gs[k] * Wl1[k*64 + t];
  h1[t] = fmaxf(acc, 0.f);
  __syncthreads();
  if (t < 10){
    float o = bl2[t];
    for (int j = 0; j < 64; j++) o += h1[j] * Wl2[j*10 + t];
    out[g*10 + t] = o;
  }
}

extern "C" void kernel_launch(void* const* d_in, const int* in_sizes, int n_in,
                              void* d_out, int out_size, void* d_ws, size_t ws_size,
                              hipStream_t stream){
  const float* pos = (const float*)d_in[0];
  const int*  ei   = (const int*)d_in[1];
  const int*  batch= (const int*)d_in[2];
  const float* W1 = (const float*)d_in[3];
  const float* b1 = (const float*)d_in[4];
  const float* W2 = (const float*)d_in[5];
  const float* b2 = (const float*)d_in[6];
  const float* W3 = (const float*)d_in[7];
  const float* b3 = (const float*)d_in[8];
  const float* Wl1 = (const float*)d_in[9];
  const float* bl1 = (const float*)d_in[10];
  const float* Wl2 = (const float*)d_in[11];
  const float* bl2 = (const float*)d_in[12];
  float* out = (float*)d_out;

  int N = in_sizes[0] / 3;     // 50000 (< 65535 required for ushort CSR + sentinel)
  int E = in_sizes[1] / 2;     // 800000
  int G = out_size / 10;       // 64
  int SB = (N + 255) / 256;    // setup blocks

  // workspace carve (~34 MB)
  char* p = (char*)d_ws;
  auto carve = [&](size_t bytes)->char* { char* q = p; p += (bytes + 255) & ~(size_t)255; return q; };
  int*            deg     = (int*)     carve(sizeof(int)    * (size_t)N);
  int*            gb      = (int*)     carve(sizeof(int)    * (size_t)(G+1));
  float*          gsum    = (float*)   carve(sizeof(float)  * (size_t)G * H);
  unsigned short* csr_src = (unsigned short*)carve(sizeof(unsigned short) * (size_t)(N+1) * CAP);
  float4*         y0      = (float4*)  carve(sizeof(float4) * (size_t)(N+1));          // +1 sentinel zero row
  ushort16*       ybufA   = (ushort16*)carve(sizeof(ushort16) * (size_t)(N+1) * H);    // +1 sentinel zero row
  ushort16*       ybufB   = (ushort16*)carve(sizeof(ushort16) * (size_t)(N+1) * H);    // +1 sentinel zero row
  ushort16*       wp2     = (ushort16*)carve(sizeof(ushort16) * 16384);
  ushort16*       wp3     = (ushort16*)carve(sizeof(ushort16) * 16384);

  const int* src = ei;
  const int* dst = ei + E;

  hipLaunchKernelGGL(k_setup, dim3(SB + 16), dim3(256), 0, stream,
                     deg, gsum, batch, N, G, gb, SB, W2, W3, wp2, wp3,
                     y0, (unsigned short*)ybufA, (unsigned short*)ybufB);

  // one-pass CSR fill (fixed capacity, 1 edge/thread: full-occupancy atomic chain hiding)
  hipLaunchKernelGGL(k_fill, dim3((E+255)/256), dim3(256), 0, stream, src, dst, E, deg, csr_src);

  // dinv prescale (needs final deg)
  hipLaunchKernelGGL(k_pre, dim3((N+255)/256), dim3(256), 0, stream, deg, pos, y0, N);

  // layer 1 (aggregate-first 3-wide gather + fused 3->128 dense)
  hipLaunchKernelGGL(k_layer1, dim3((N+255)/256), dim3(256), 0, stream, y0, deg, csr_src, W1, b1, ybufA, N);

  // layer 2 (fused aggregate + MFMA, bf16 y out via LDS-staged coalesced store)
  hipLaunchKernelGGL(k_aggdense<0>, dim3((N+15)/16), dim3(256), 0, stream,
                     ybufA, deg, csr_src, wp2, b2, ybufB, (const int*)nullptr, (float*)nullptr, N);

  // layer 3 (fused aggregate + MFMA + mean-pool numerator into gsum)
  hipLaunchKernelGGL(k_aggdense<1>, dim3((N+15)/16), dim3(256), 0, stream,
                     ybufB, deg, csr_src, wp3, b3, (ushort16*)nullptr, batch, gsum, N);

  hipLaunchKernelGGL(k_head, dim3(G), dim3(64), 0, stream, gsum, gb, Wl1, bl1, Wl2, bl2, out);
}

// Round 9
// 225.836 us; speedup vs baseline: 1.0278x; 1.0145x over previous
//
#include <hip/hip_runtime.h>

#define H 128
#define CAP 64        // fixed CSR capacity per node (Poisson(16) in-deg: P(>=64) ~ 1e-17)
#define LSTRIDE 136   // LDS row stride in bf16 elems: 272B, 16B-aligned, 2-way bank (free)
#define PSTR 132      // pool stride in floats: rl*132 -> bank offset rl*4, 2-way (free)
typedef unsigned int uint32;
typedef unsigned short ushort16;
typedef __attribute__((ext_vector_type(8))) short bf16x8;
typedef __attribute__((ext_vector_type(4))) float f32x4;

static __device__ __forceinline__ ushort16 f2bf(float f){
  uint32 u = __float_as_uint(f);
  uint32 r = (u + 0x7fff + ((u >> 16) & 1)) >> 16;   // RNE bf16 (finite values)
  return (ushort16)r;
}
static __device__ __forceinline__ float bflo(uint32 u){ return __uint_as_float(u << 16); }
static __device__ __forceinline__ float bfhi(uint32 u){ return __uint_as_float(u & 0xffff0000u); }

// fused setup: deg=0, gsum=0, gb[0..G]; zero sentinel rows (y0[N], ybufA[N], ybufB[N]);
// last 16 blocks prep W2/W3 into MFMA B-frag bf16.
__global__ __launch_bounds__(256) void k_setup(int* __restrict__ deg, float* __restrict__ gsum,
                                               const int* __restrict__ batch, int n, int G,
                                               int* __restrict__ gb, int SB,
                                               const float* __restrict__ W2, const float* __restrict__ W3,
                                               ushort16* __restrict__ wp2, ushort16* __restrict__ wp3,
                                               float4* __restrict__ y0,
                                               unsigned short* __restrict__ ybA,
                                               unsigned short* __restrict__ ybB){
  int b = blockIdx.x;
  if (b < SB){
    int i = b*256 + threadIdx.x;
    if (i < n) deg[i] = 0;
    if (i < G*H) gsum[i] = 0.f;
    if (i < H){ ybA[(size_t)n*H + i] = 0; ybB[(size_t)n*H + i] = 0; }
    if (i == 0) y0[n] = make_float4(0.f, 0.f, 0.f, 0.f);
    if (i <= G){
      int lo = 0, hi = n;
      while (lo < hi){ int m = (lo + hi) >> 1; if (batch[m] < i) lo = m + 1; else hi = m; }
      gb[i] = lo;
    }
  } else {
    int gid = (b - SB)*256 + threadIdx.x;   // 0..4095
    const float* W = (gid < 2048) ? W2 : W3;
    ushort16* wp   = (gid < 2048) ? wp2 : wp3;
    int tid = gid & 2047;
    int frag = tid >> 6, lane = tid & 63;
    int kt = frag >> 3, ct = frag & 7;
    int m = lane & 15, quad = lane >> 4;
    const float* wrow = &W[(kt*32 + quad*8)*H + ct*16 + m];
    ushort16 vals[8];
    #pragma unroll
    for (int j = 0; j < 8; j++) vals[j] = f2bf(wrow[j*H]);
    uint4 o;
    o.x = (uint32)vals[0] | ((uint32)vals[1] << 16);
    o.y = (uint32)vals[2] | ((uint32)vals[3] << 16);
    o.z = (uint32)vals[4] | ((uint32)vals[5] << 16);
    o.w = (uint32)vals[6] | ((uint32)vals[7] << 16);
    *(uint4*)&wp[(size_t)tid*8] = o;
  }
}

// XCD-local CSR fill: blockIdx&7 = dst-range partition; with round-robin block->XCD
// dispatch, all stores to one CSR bucket issue from ONE XCD -> one L2 writeback per
// sector instead of ~7 (R8 counters: WRITE_SIZE 44MB for 1.6MB payload).
// Each partition scans the full dst[] (coalesced int4); only matching edges scatter.
__global__ __launch_bounds__(256) void k_fill(const int* __restrict__ src, const int* __restrict__ dst,
                                              int E, int NP8, int* __restrict__ deg,
                                              unsigned short* __restrict__ csr_src){
  int part = blockIdx.x & 7;
  int plo = part * NP8, phi = plo + NP8;   // dst range owned by this partition
  int base = (blockIdx.x >> 3)*1024 + threadIdx.x*4;
  if (base + 3 < E){
    int4 d = *(const int4*)&dst[base];
    if (d.x >= plo && d.x < phi){
      int slot = atomicAdd(&deg[d.x], 1);
      if (slot < CAP) csr_src[((size_t)d.x << 6) + slot] = (unsigned short)src[base+0];
    }
    if (d.y >= plo && d.y < phi){
      int slot = atomicAdd(&deg[d.y], 1);
      if (slot < CAP) csr_src[((size_t)d.y << 6) + slot] = (unsigned short)src[base+1];
    }
    if (d.z >= plo && d.z < phi){
      int slot = atomicAdd(&deg[d.z], 1);
      if (slot < CAP) csr_src[((size_t)d.z << 6) + slot] = (unsigned short)src[base+2];
    }
    if (d.w >= plo && d.w < phi){
      int slot = atomicAdd(&deg[d.w], 1);
      if (slot < CAP) csr_src[((size_t)d.w << 6) + slot] = (unsigned short)src[base+3];
    }
  } else if (base < E){
    for (int i = base; i < E; i++){
      int d = dst[i];
      if (d >= plo && d < phi){
        int slot = atomicAdd(&deg[d], 1);
        if (slot < CAP) csr_src[((size_t)d << 6) + slot] = (unsigned short)src[i];
      }
    }
  }
}

// dinv prescale: y0[i] = rsqrt(deg[i]+1) * pos[i]
__global__ __launch_bounds__(256) void k_pre(const int* __restrict__ deg, const float* __restrict__ pos,
                                             float4* __restrict__ y0, int n){
  int i = blockIdx.x*256 + threadIdx.x;
  if (i < n){
    float dv = rsqrtf((float)(deg[i] + 1));
    y0[i] = make_float4(pos[3*i]*dv, pos[3*i+1]*dv, pos[3*i+2]*dv, 0.f);
  }
}

// Fused layer 1: per node, a = dinv * (y0[node] + sum_src y0[src]), then
// y1[node,c] = bf16( dinv * relu(a . W1[:,c] + b1[c]) ) for all 128 cols (W1/b1 wave-uniform).
// Self-contribution added directly; tail chunk index-clamped to sentinel n (zero row).
__global__ __launch_bounds__(256) void k_layer1(const float4* __restrict__ y0, const int* __restrict__ deg,
      const unsigned short* __restrict__ csr_src,
      const float* __restrict__ W1, const float* __restrict__ b1,
      ushort16* __restrict__ y1, int n){
  int node = blockIdx.x*256 + threadIdx.x;
  if (node >= n) return;
  int cnt = deg[node];
  int lo = node << 6;
  float4 own = y0[node];
  float x = own.x, y = own.y, z = own.z;
  int mm = cnt > CAP ? CAP : cnt;
  int nfull = mm >> 3, rem = mm & 7;
  #define GADD(s0,s1,s2,s3,s4,s5,s6,s7) { \
    float4 v0 = y0[s0], v1 = y0[s1], v2 = y0[s2], v3 = y0[s3]; \
    float4 v4 = y0[s4], v5 = y0[s5], v6 = y0[s6], v7 = y0[s7]; \
    x += ((v0.x+v1.x)+(v2.x+v3.x)) + ((v4.x+v5.x)+(v6.x+v7.x)); \
    y += ((v0.y+v1.y)+(v2.y+v3.y)) + ((v4.y+v5.y)+(v6.y+v7.y)); \
    z += ((v0.z+v1.z)+(v2.z+v3.z)) + ((v4.z+v5.z)+(v6.z+v7.z)); }
  if (rem){
    uint4 iv = *(const uint4*)&csr_src[lo + nfull*8];
    int s0 = (int)(iv.x & 0xffff);
    int s1 = (1 < rem)? (int)(iv.x >> 16)    : n;
    int s2 = (2 < rem)? (int)(iv.y & 0xffff) : n;
    int s3 = (3 < rem)? (int)(iv.y >> 16)    : n;
    int s4 = (4 < rem)? (int)(iv.z & 0xffff) : n;
    int s5 = (5 < rem)? (int)(iv.z >> 16)    : n;
    int s6 = (6 < rem)? (int)(iv.w & 0xffff) : n;
    int s7 = (7 < rem)? (int)(iv.w >> 16)    : n;
    GADD(s0,s1,s2,s3,s4,s5,s6,s7);
  }
  if (nfull){
    uint4 iv = *(const uint4*)&csr_src[lo];
    for (int c = 0; c < nfull; c++){
      uint4 nx = *(const uint4*)&csr_src[lo + c*8 + 8];  // prefetch (stays inside (N+1)*64 slots)
      int s0 = iv.x & 0xffff, s1 = iv.x >> 16;
      int s2 = iv.y & 0xffff, s3 = iv.y >> 16;
      int s4 = iv.z & 0xffff, s5 = iv.z >> 16;
      int s6 = iv.w & 0xffff, s7 = iv.w >> 16;
      GADD(s0,s1,s2,s3,s4,s5,s6,s7);
      iv = nx;
    }
  }
  #undef GADD
  float dn = rsqrtf((float)(cnt + 1));
  x *= dn; y *= dn; z *= dn;
  ushort16* rowp = &y1[(size_t)node*H];
  for (int c8 = 0; c8 < 16; c8++){
    float4 wa0 = *(const float4*)&W1[c8*8];
    float4 wa1 = *(const float4*)&W1[c8*8+4];
    float4 wb0 = *(const float4*)&W1[H + c8*8];
    float4 wb1 = *(const float4*)&W1[H + c8*8+4];
    float4 wc0 = *(const float4*)&W1[2*H + c8*8];
    float4 wc1 = *(const float4*)&W1[2*H + c8*8+4];
    float4 bb0 = *(const float4*)&b1[c8*8];
    float4 bb1 = *(const float4*)&b1[c8*8+4];
    float o0 = fmaxf(x*wa0.x + y*wb0.x + z*wc0.x + bb0.x, 0.f) * dn;
    float o1 = fmaxf(x*wa0.y + y*wb0.y + z*wc0.y + bb0.y, 0.f) * dn;
    float o2 = fmaxf(x*wa0.z + y*wb0.z + z*wc0.z + bb0.z, 0.f) * dn;
    float o3 = fmaxf(x*wa0.w + y*wb0.w + z*wc0.w + bb0.w, 0.f) * dn;
    float o4 = fmaxf(x*wa1.x + y*wb1.x + z*wc1.x + bb1.x, 0.f) * dn;
    float o5 = fmaxf(x*wa1.y + y*wb1.y + z*wc1.y + bb1.y, 0.f) * dn;
    float o6 = fmaxf(x*wa1.z + y*wb1.z + z*wc1.z + bb1.z, 0.f) * dn;
    float o7 = fmaxf(x*wa1.w + y*wb1.w + z*wc1.w + bb1.w, 0.f) * dn;
    uint4 o;
    o.x = (uint32)f2bf(o0) | ((uint32)f2bf(o1) << 16);
    o.y = (uint32)f2bf(o2) | ((uint32)f2bf(o3) << 16);
    o.z = (uint32)f2bf(o4) | ((uint32)f2bf(o5) << 16);
    o.w = (uint32)f2bf(o6) | ((uint32)f2bf(o7) << 16);
    *(uint4*)&rowp[c8*8] = o;
  }
}

// Fused aggregate + MFMA dense (full gather parallelism: 16 nodes/block, 16 lanes/node, one pass).
// Self row added directly (coalesced); tail chunk clamped to sentinel n (zero row).
// POOL=0: yout tile staged in LDS then coalesced 16B/lane bf16 stores (layer 2)
// POOL=1: relu(aW+b) -> LDS tile -> parallel segmented atomicAdd into gsum (layer 3 + pool numerator)
template<int POOL>
__global__ __launch_bounds__(256) void k_aggdense(const ushort16* __restrict__ y, const int* __restrict__ deg,
      const unsigned short* __restrict__ csr_src, const ushort16* __restrict__ wp,
      const float* __restrict__ bias,
      ushort16* __restrict__ yout, const int* __restrict__ batch, float* __restrict__ gsum, int n){
  __shared__ unsigned short As[16*LSTRIDE];          // 4352 B
  __shared__ float pool[POOL ? 16*PSTR : 1];         // 8448 B (POOL only)
  __shared__ unsigned short outs[POOL ? 1 : 16*PSTR];// 4224 B (non-POOL: staged bf16 out tile)
  __shared__ int sbatch[POOL ? 16 : 1];
  __shared__ float sdinv[POOL ? 1 : 16];
  int tid = threadIdx.x;
  int node16 = blockIdx.x*16;
  int nl = tid >> 4;                 // local node 0..15
  int node = node16 + nl;
  int f8 = (tid & 15) * 8;

  if (tid < 16){
    int nn = node16 + tid;
    if (POOL) sbatch[tid] = (nn < n) ? batch[nn] : -1;
    else      sdinv[tid]  = (nn < n) ? rsqrtf((float)(deg[nn] + 1)) : 0.f;
  }

  // ---- phase A: aggregate (self row + branchless 8-wide chunks, clamped tail first) ----
  float a0=0,a1=0,a2=0,a3=0,a4=0,a5=0,a6=0,a7=0;
  float dn = 0.f;
  #define ADDU(u) { a0+=bflo(u.x); a1+=bfhi(u.x); a2+=bflo(u.y); a3+=bfhi(u.y); \
                    a4+=bflo(u.z); a5+=bfhi(u.z); a6+=bflo(u.w); a7+=bfhi(u.w); }
  #define GATHER8(s0,s1,s2,s3,s4,s5,s6,s7) { \
    uint4 u0 = *(const uint4*)&y[(size_t)(s0)*H + f8]; \
    uint4 u1 = *(const uint4*)&y[(size_t)(s1)*H + f8]; \
    uint4 u2 = *(const uint4*)&y[(size_t)(s2)*H + f8]; \
    uint4 u3 = *(const uint4*)&y[(size_t)(s3)*H + f8]; \
    uint4 u4 = *(const uint4*)&y[(size_t)(s4)*H + f8]; \
    uint4 u5 = *(const uint4*)&y[(size_t)(s5)*H + f8]; \
    uint4 u6 = *(const uint4*)&y[(size_t)(s6)*H + f8]; \
    uint4 u7 = *(const uint4*)&y[(size_t)(s7)*H + f8]; \
    ADDU(u0); ADDU(u1); ADDU(u2); ADDU(u3); \
    ADDU(u4); ADDU(u5); ADDU(u6); ADDU(u7); }
  if (node < n){
    int cnt = deg[node];
    int lo = node << 6;
    dn = rsqrtf((float)(cnt + 1));
    uint4 uo = *(const uint4*)&y[(size_t)node*H + f8];   // self row (coalesced)
    ADDU(uo);
    int mm = cnt > CAP ? CAP : cnt;
    int nfull = mm >> 3, rem = mm & 7;
    if (rem){
      uint4 iv = *(const uint4*)&csr_src[lo + nfull*8];
      int s0 = (int)(iv.x & 0xffff);
      int s1 = (1 < rem)? (int)(iv.x >> 16)    : n;
      int s2 = (2 < rem)? (int)(iv.y & 0xffff) : n;
      int s3 = (3 < rem)? (int)(iv.y >> 16)    : n;
      int s4 = (4 < rem)? (int)(iv.z & 0xffff) : n;
      int s5 = (5 < rem)? (int)(iv.z >> 16)    : n;
      int s6 = (6 < rem)? (int)(iv.w & 0xffff) : n;
      int s7 = (7 < rem)? (int)(iv.w >> 16)    : n;
      GATHER8(s0,s1,s2,s3,s4,s5,s6,s7);
    }
    if (nfull){
      uint4 iv = *(const uint4*)&csr_src[lo];
      for (int c = 0; c < nfull; c++){
        uint4 nx = *(const uint4*)&csr_src[lo + c*8 + 8];  // prefetch next chunk's indices
        int s0 = iv.x & 0xffff, s1 = iv.x >> 16;
        int s2 = iv.y & 0xffff, s3 = iv.y >> 16;
        int s4 = iv.z & 0xffff, s5 = iv.z >> 16;
        int s6 = iv.w & 0xffff, s7 = iv.w >> 16;
        GATHER8(s0,s1,s2,s3,s4,s5,s6,s7);
        iv = nx;
      }
    }
  }
  #undef GATHER8
  #undef ADDU
  uint4 o;
  o.x = (uint32)f2bf(a0*dn) | ((uint32)f2bf(a1*dn) << 16);
  o.y = (uint32)f2bf(a2*dn) | ((uint32)f2bf(a3*dn) << 16);
  o.z = (uint32)f2bf(a4*dn) | ((uint32)f2bf(a5*dn) << 16);
  o.w = (uint32)f2bf(a6*dn) | ((uint32)f2bf(a7*dn) << 16);
  *(uint4*)&As[nl*LSTRIDE + f8] = o;
  __syncthreads();

  // ---- phase B: MFMA — wave w handles col-tiles {2w, 2w+1} over the 16 staged rows ----
  int wave = tid >> 6;
  int lane = tid & 63;
  int m = lane & 15, quad = lane >> 4;
  f32x4 acc0 = {0.f,0.f,0.f,0.f}, acc1 = {0.f,0.f,0.f,0.f};
  int ct0 = wave*2, ct1 = wave*2 + 1;
  #pragma unroll
  for (int kt = 0; kt < 4; kt++){
    bf16x8 af = *(const bf16x8*)&As[m*LSTRIDE + kt*32 + quad*8];
    bf16x8 b0 = *(const bf16x8*)&wp[(size_t)((kt*8+ct0)*64 + lane)*8];
    bf16x8 b1 = *(const bf16x8*)&wp[(size_t)((kt*8+ct1)*64 + lane)*8];
    acc0 = __builtin_amdgcn_mfma_f32_16x16x32_bf16(af, b0, acc0, 0, 0, 0);
    acc1 = __builtin_amdgcn_mfma_f32_16x16x32_bf16(af, b1, acc1, 0, 0, 0);
  }
  // C/D layout: col = ct*16 + m, row (in tile) = quad*4 + r
  #pragma unroll
  for (int j = 0; j < 2; j++){
    int ct = wave*2 + j;
    int col = ct*16 + m;
    float bv = bias[col];
    f32x4 ac = j ? acc1 : acc0;
    #pragma unroll
    for (int r = 0; r < 4; r++){
      int rl = quad*4 + r;
      int orow = node16 + rl;
      if (orow < n){
        float v = fmaxf(ac[r] + bv, 0.f);
        if (POOL) pool[rl*PSTR + col] = v;                            // one lane per (row,col)
        else      outs[rl*PSTR + col] = f2bf(v * sdinv[rl]);
      }
    }
  }
  __syncthreads();
  if (POOL){
    // parallel segmented tail: 256 threads = 128 cols x 2 row-halves
    int col = tid & 127;
    int half = tid >> 7;
    float run = 0.f; int gprev = -1;
    for (int r = half*8; r < half*8 + 8; r++){
      int g = sbatch[r];
      if (g < 0) break;            // tail rows only
      if (g != gprev){
        if (gprev >= 0) atomicAdd(&gsum[gprev*H + col], run);
        run = 0.f; gprev = g;
      }
      run += pool[r*PSTR + col];
    }
    if (gprev >= 0) atomicAdd(&gsum[gprev*H + col], run);
  } else {
    // coalesced store: thread t writes row t>>4, 8 bf16 at (t&15)*8
    int row = tid >> 4;
    int orow = node16 + row;
    if (orow < n){
      const unsigned short* sp = &outs[row*PSTR + f8];
      uint4 v;
      v.x = (uint32)sp[0] | ((uint32)sp[1] << 16);
      v.y = (uint32)sp[2] | ((uint32)sp[3] << 16);
      v.z = (uint32)sp[4] | ((uint32)sp[5] << 16);
      v.w = (uint32)sp[6] | ((uint32)sp[7] << 16);
      *(uint4*)&yout[(size_t)orow*H + f8] = v;
    }
  }
}

// MLP head: relu((gsum/cnt) @ Wl1 + bl1) @ Wl2 + bl2
__global__ __launch_bounds__(64) void k_head(const float* __restrict__ gsum, const int* __restrict__ gb,
            const float* __restrict__ Wl1, const float* __restrict__ bl1,
            const float* __restrict__ Wl2, const float* __restrict__ bl2,
            float* __restrict__ out){
  int g = blockIdx.x;
  int t = threadIdx.x;
  __shared__ float gs[H];
  __shared__ float h1[64];
  float inv = 1.f / fmaxf((float)(gb[g+1] - gb[g]), 1.f);
  gs[t]      = gsum[g*H + t]      * inv;
  gs[64 + t] = gsum[g*H + 64 + t] * inv;
  __syncthreads();
  float acc = bl1[t];
  for (int k = 0; k < H; k++) acc += gs[k] * Wl1[k*64 + t];
  h1[t] = fmaxf(acc, 0.f);
  __syncthreads();
  if (t < 10){
    float o = bl2[t];
    for (int j = 0; j < 64; j++) o += h1[j] * Wl2[j*10 + t];
    out[g*10 + t] = o;
  }
}

extern "C" void kernel_launch(void* const* d_in, const int* in_sizes, int n_in,
                              void* d_out, int out_size, void* d_ws, size_t ws_size,
                              hipStream_t stream){
  const float* pos = (const float*)d_in[0];
  const int*  ei   = (const int*)d_in[1];
  const int*  batch= (const int*)d_in[2];
  const float* W1 = (const float*)d_in[3];
  const float* b1 = (const float*)d_in[4];
  const float* W2 = (const float*)d_in[5];
  const float* b2 = (const float*)d_in[6];
  const float* W3 = (const float*)d_in[7];
  const float* b3 = (const float*)d_in[8];
  const float* Wl1 = (const float*)d_in[9];
  const float* bl1 = (const float*)d_in[10];
  const float* Wl2 = (const float*)d_in[11];
  const float* bl2 = (const float*)d_in[12];
  float* out = (float*)d_out;

  int N = in_sizes[0] / 3;     // 50000 (< 65535 required for ushort CSR + sentinel)
  int E = in_sizes[1] / 2;     // 800000
  int G = out_size / 10;       // 64
  int SB = (N + 255) / 256;    // setup blocks
  int NP8 = (N + 7) / 8;       // dst-range width per XCD partition
  int NCH = (E + 1023) / 1024; // edge chunks (1024 edges per block)

  // workspace carve (~34 MB)
  char* p = (char*)d_ws;
  auto carve = [&](size_t bytes)->char* { char* q = p; p += (bytes + 255) & ~(size_t)255; return q; };
  int*            deg     = (int*)     carve(sizeof(int)    * (size_t)N);
  int*            gb      = (int*)     carve(sizeof(int)    * (size_t)(G+1));
  float*          gsum    = (float*)   carve(sizeof(float)  * (size_t)G * H);
  unsigned short* csr_src = (unsigned short*)carve(sizeof(unsigned short) * (size_t)(N+1) * CAP);
  float4*         y0      = (float4*)  carve(sizeof(float4) * (size_t)(N+1));          // +1 sentinel zero row
  ushort16*       ybufA   = (ushort16*)carve(sizeof(ushort16) * (size_t)(N+1) * H);    // +1 sentinel zero row
  ushort16*       ybufB   = (ushort16*)carve(sizeof(ushort16) * (size_t)(N+1) * H);    // +1 sentinel zero row
  ushort16*       wp2     = (ushort16*)carve(sizeof(ushort16) * 16384);
  ushort16*       wp3     = (ushort16*)carve(sizeof(ushort16) * 16384);

  const int* src = ei;
  const int* dst = ei + E;

  hipLaunchKernelGGL(k_setup, dim3(SB + 16), dim3(256), 0, stream,
                     deg, gsum, batch, N, G, gb, SB, W2, W3, wp2, wp3,
                     y0, (unsigned short*)ybufA, (unsigned short*)ybufB);

  // XCD-local CSR fill: 8 dst-partitions x edge chunks; blockIdx&7 = partition
  hipLaunchKernelGGL(k_fill, dim3(NCH*8), dim3(256), 0, stream, src, dst, E, NP8, deg, csr_src);

  // dinv prescale (needs final deg)
  hipLaunchKernelGGL(k_pre, dim3((N+255)/256), dim3(256), 0, stream, deg, pos, y0, N);

  // layer 1 (aggregate-first 3-wide gather + fused 3->128 dense)
  hipLaunchKernelGGL(k_layer1, dim3((N+255)/256), dim3(256), 0, stream, y0, deg, csr_src, W1, b1, ybufA, N);

  // layer 2 (fused aggregate + MFMA, bf16 y out via LDS-staged coalesced store)
  hipLaunchKernelGGL(k_aggdense<0>, dim3((N+15)/16), dim3(256), 0, stream,
                     ybufA, deg, csr_src, wp2, b2, ybufB, (const int*)nullptr, (float*)nullptr, N);

  // layer 3 (fused aggregate + MFMA + mean-pool numerator into gsum)
  hipLaunchKernelGGL(k_aggdense<1>, dim3((N+15)/16), dim3(256), 0, stream,
                     ybufB, deg, csr_src, wp3, b3, (ushort16*)nullptr, batch, gsum, N);

  hipLaunchKernelGGL(k_head, dim3(G), dim3(64), 0, stream, gsum, gb, Wl1, bl1, Wl2, bl2, out);
}